// Round 3
// baseline (920.943 us; speedup 1.0000x reference)
//
#include <hip/hip_runtime.h>
#include <stdint.h>

#define B 8
#define N 8192
#define NG 512
#define GS 32

typedef unsigned long long ull;
typedef float v2f __attribute__((ext_vector_type(2)));

// Exact (no-FMA, left-to-right) squared distance: ((dx*dx + dy*dy) + dz*dz)
__device__ __forceinline__ float sq3(float dx, float dy, float dz) {
#pragma clang fp contract(off)
  return dx * dx + dy * dy + dz * dz;
}

// 64-bit max via DPP move (pure VALU, no LDS pipe). Invalid lanes keep old.
template <int CTRL>
__device__ __forceinline__ ull dpp_max64(ull key) {
  unsigned lo = (unsigned)key, hi = (unsigned)(key >> 32);
  unsigned olo = (unsigned)__builtin_amdgcn_update_dpp((int)lo, (int)lo, CTRL, 0xf, 0xf, false);
  unsigned ohi = (unsigned)__builtin_amdgcn_update_dpp((int)hi, (int)hi, CTRL, 0xf, 0xf, false);
  ull o = ((ull)ohi << 32) | olo;
  return (o > key) ? o : key;
}

// ---------------- Kernel 1: SE(3) transform, AoS xyz -> SoA xs/ys/zs ------
// Also zeroes the FPS cross-block comm slots (stream-ordered before fps_k).
__global__ void transform_k(const float* __restrict__ xyz,
                            const float* __restrict__ pose,
                            float* __restrict__ xs, float* __restrict__ ys,
                            float* __restrict__ zs, ull* __restrict__ comm) {
#pragma clang fp contract(off)
  if (blockIdx.x == 0 && threadIdx.x < 64) comm[threadIdx.x] = 0ull;
  int i = blockIdx.x * blockDim.x + threadIdx.x;
  if (i >= B * N) return;
  int b = i / N;
  const float* P = pose + b * 12;  // (3,4) row-major: R|t
  float p0 = xyz[i * 3 + 0], p1 = xyz[i * 3 + 1], p2 = xyz[i * 3 + 2];
  // exact order: ((r0*p0 + r1*p1) + r2*p2) + t
  float ox = ((P[0] * p0 + P[1] * p1) + P[2] * p2) + P[3];
  float oy = ((P[4] * p0 + P[5] * p1) + P[6] * p2) + P[7];
  float oz = ((P[8] * p0 + P[9] * p1) + P[10] * p2) + P[11];
  xs[i] = ox;
  ys[i] = oy;
  zs[i] = oz;
}

// ---------------- Kernel 2: farthest point sampling, 4 blocks per batch ---
// Each block scans a 2048-point partition (registers) and mirrors all 8192
// points in LDS for winner-coord lookup. Per step, blocks exchange a single
// relaxed device-scope 64-bit word: (distbits<<32)|((8191-idx)<<19)|(seq<<9).
// u64 max over same-step words == (max dist, tie -> min idx). Slots are
// double-buffered by step parity; skew is bounded to one publish, so no
// overwrite-before-read and no deadlock.
#define FPS_T 256
#define FPS_Q 4                  // blocks per batch
#define FPS_W (FPS_T / 64)       // 4 waves
#define FPS_JT (N / FPS_T / 2)   // 16 v2f per thread (full-mirror load)
#define FPS_JL (FPS_JT / FPS_Q)  // 4 v2f per thread (local scan partition)

__global__ __launch_bounds__(FPS_T) void fps_k(const float* __restrict__ xs,
                                               const float* __restrict__ ys,
                                               const float* __restrict__ zs,
                                               float* __restrict__ centers,
                                               ull* __restrict__ comm) {
#pragma clang fp contract(off)
  int bid = blockIdx.x;
  int b = bid >> 2, q = bid & 3;  // batch, quarter
  int t = threadIdx.x;

  __shared__ float plx[N];        // LDS mirror of the FULL batch (SoA)
  __shared__ float ply[N];
  __shared__ float plz[N];
  __shared__ ull wkey[2][FPS_W];  // double-buffered per-wave winner keys

  const float* __restrict__ bx = xs + b * N;
  const float* __restrict__ by = ys + b * N;
  const float* __restrict__ bz = zs + b * N;
  const v2f* __restrict__ bx2 = (const v2f*)bx;
  const v2f* __restrict__ by2 = (const v2f*)by;
  const v2f* __restrict__ bz2 = (const v2f*)bz;

  // Full-batch mirror load; keep our quarter (v2f j in [4q, 4q+4)) in regs.
  v2f px[FPS_JL], py[FPS_JL], pz[FPS_JL], dist[FPS_JL];
#pragma unroll
  for (int j = 0; j < FPS_JT; ++j) {
    int qq = j * FPS_T + t;
    v2f vx = bx2[qq], vy = by2[qq], vz = bz2[qq];
    ((v2f*)plx)[qq] = vx;
    ((v2f*)ply)[qq] = vy;
    ((v2f*)plz)[qq] = vz;
    if ((j >> 2) == q) {
      int jl = j & 3;
      px[jl] = vx;
      py[jl] = vy;
      pz[jl] = vz;
      dist[jl].x = 1e10f;  // matches jnp.full(..., 1e10, f32)
      dist[jl].y = 1e10f;
    }
  }

  // initial "last" point is index 0 (broadcast global load, off critical path)
  float lx = bx[0], ly = by[0], lz = bz[0];
  ull* slots = comm + b * (2 * FPS_Q);  // [parity][q]
  __syncthreads();  // LDS mirror ready

  for (int k = 0; k < NG; ++k) {
    if (q == 0 && t == 0) {  // emit 'last' BEFORE update; posted store
      int o = (b * NG + k) * 3;
      centers[o + 0] = lx;
      centers[o + 1] = ly;
      centers[o + 2] = lz;
    }

    // Fused exact min-update + first-occurrence argmax over our quarter.
    // 2 accumulators; codes (2j+e) ascend in processing order per acc, and
    // global index is monotone in code => strict '>' keeps first occurrence.
    float bd0 = -1.0f, bd1 = -1.0f;
    int bc0 = 0, bc1 = 0;
#pragma unroll
    for (int j = 0; j < FPS_JL; ++j) {
      v2f dx = px[j] - lx, dy = py[j] - ly, dz = pz[j] - lz;
      v2f d = (dx * dx + dy * dy) + dz * dz;
      v2f dm;
      dm.x = fminf(dist[j].x, d.x);
      dm.y = fminf(dist[j].y, d.y);
      dist[j] = dm;
      float* bdp = (j & 1) ? &bd1 : &bd0;
      int* bcp = (j & 1) ? &bc1 : &bc0;
      bool g0 = dm.x > *bdp;
      *bdp = g0 ? dm.x : *bdp;
      *bcp = g0 ? (2 * j) : *bcp;
      bool g1 = dm.y > *bdp;
      *bdp = g1 ? dm.y : *bdp;
      *bcp = g1 ? (2 * j + 1) : *bcp;
    }
    {  // tie-aware merge: equal dist -> smaller code
      bool s1 = (bd1 > bd0) || ((bd1 == bd0) && (bc1 < bc0));
      bd0 = s1 ? bd1 : bd0;
      bc0 = s1 ? bc1 : bc0;
    }
    // global point index: ((q*4 + j)*FPS_T + t)*2 + e
    int cand = ((q * FPS_JL + (bc0 >> 1)) * FPS_T + t) * 2 + (bc0 & 1);
    // pack: max over key == max dist, tie -> min index
    ull key = ((ull)__float_as_uint(bd0) << 32) | (ull)(unsigned)(N - 1 - cand);

    // wave-level max via DPP (VALU only): row_shr 1/2/4/8, bcast 15/31
    key = dpp_max64<0x111>(key);
    key = dpp_max64<0x112>(key);
    key = dpp_max64<0x114>(key);
    key = dpp_max64<0x118>(key);
    key = dpp_max64<0x142>(key);
    key = dpp_max64<0x143>(key);
    unsigned klo = (unsigned)__builtin_amdgcn_readlane((int)(unsigned)key, 63);
    unsigned khi = (unsigned)__builtin_amdgcn_readlane((int)(unsigned)(key >> 32), 63);
    ull wk = ((ull)khi << 32) | klo;

    int kb = k & 1;
    if ((t & 63) == 0) wkey[kb][t >> 6] = wk;
    __syncthreads();

    // block-level merge (keys only)
    ull bk = wkey[kb][0];
#pragma unroll
    for (int w = 1; w < FPS_W; ++w) {
      ull o = wkey[kb][w];
      bk = (o > bk) ? o : bk;
    }

    // publish our block's winner: one relaxed agent-scope 64-bit word
    ull pub = (bk & 0xFFFFFFFF00000000ull) | ((bk & 0x1FFFull) << 19) |
              ((ull)(unsigned)(k + 1) << 9);
    if (t == 0)
      __hip_atomic_store(&slots[kb * FPS_Q + q], pub, __ATOMIC_RELAXED,
                         __HIP_MEMORY_SCOPE_AGENT);

    // poll the 3 foreign slots (same parity) until their seq == k+1
    int f0 = kb * FPS_Q + ((q + 1) & 3);
    int f1 = kb * FPS_Q + ((q + 2) & 3);
    int f2 = kb * FPS_Q + ((q + 3) & 3);
    unsigned want = (unsigned)(k + 1) & 0x3FFu;
    ull v0, v1, v2;
    do {
      v0 = __hip_atomic_load(&slots[f0], __ATOMIC_RELAXED, __HIP_MEMORY_SCOPE_AGENT);
      v1 = __hip_atomic_load(&slots[f1], __ATOMIC_RELAXED, __HIP_MEMORY_SCOPE_AGENT);
      v2 = __hip_atomic_load(&slots[f2], __ATOMIC_RELAXED, __HIP_MEMORY_SCOPE_AGENT);
    } while ((((unsigned)(v0 >> 9) & 0x3FFu) != want) |
             (((unsigned)(v1 >> 9) & 0x3FFu) != want) |
             (((unsigned)(v2 >> 9) & 0x3FFu) != want));

    // global winner = u64 max (same seq bits cancel); decode and fetch coords
    ull m = (v0 > pub) ? v0 : pub;
    m = (v1 > m) ? v1 : m;
    m = (v2 > m) ? v2 : m;
    int wi = (N - 1) - (int)((m >> 19) & 0x1FFF);
    lx = plx[wi];
    ly = ply[wi];
    lz = plz[wi];
  }
}

// ---------------- Kernel 3: exact 32-NN per center, 1 block per center ----
#define KNN_T 256
#define KNN_P (N / KNN_T)  // 32 points per thread

__global__ __launch_bounds__(KNN_T) void knn_k(const float* __restrict__ xs,
                                               const float* __restrict__ ys,
                                               const float* __restrict__ zs,
                                               const float* __restrict__ centers,
                                               float* __restrict__ out) {
#pragma clang fp contract(off)
  int b = blockIdx.y, g = blockIdx.x, t = threadIdx.x;
  const float* bx = xs + b * N;
  const float* by = ys + b * N;
  const float* bz = zs + b * N;
  int ci = (b * NG + g) * 3;
  float cx = centers[ci], cy = centers[ci + 1], cz = centers[ci + 2];

  // packed keys: (distBits<<32)|idx ; min over key == min dist, tie -> min idx
  ull key[KNN_P];
  ull lmin = ~0ull;
#pragma unroll
  for (int j = 0; j < KNN_P; ++j) {
    int p = j * KNN_T + t;
    float dx = bx[p] - cx, dy = by[p] - cy, dz = bz[p] - cz;
    float d = sq3(dx, dy, dz);
    key[j] = ((ull)__float_as_uint(d) << 32) | (ull)(unsigned)p;
    lmin = (key[j] < lmin) ? key[j] : lmin;
  }

  __shared__ ull wred[KNN_T / 64];
  __shared__ int widx[GS];

  for (int k = 0; k < GS; ++k) {
    ull v = lmin;
#pragma unroll
    for (int off = 32; off >= 1; off >>= 1) {
      ull o = __shfl_xor(v, off, 64);
      v = (o < v) ? o : v;
    }
    if ((t & 63) == 0) wred[t >> 6] = v;
    __syncthreads();

    ull gm = wred[0];
#pragma unroll
    for (int w = 1; w < KNN_T / 64; ++w) {
      ull o = wred[w];
      gm = (o < gm) ? o : gm;
    }
    int idx = (int)(unsigned)gm;

    // only the owning lane rescans its keys (cached local min elsewhere)
    if (t == (idx & (KNN_T - 1))) {
      int jj = idx / KNN_T;
#pragma unroll
      for (int j = 0; j < KNN_P; ++j)
        if (j == jj) key[j] = ~0ull;
      lmin = ~0ull;
#pragma unroll
      for (int j = 0; j < KNN_P; ++j) lmin = (key[j] < lmin) ? key[j] : lmin;
    }
    if (t == 0) widx[k] = idx;
    __syncthreads();
  }

  // gather & write neighborhood (B, NG, GS, 3), k ascending by (d, idx)
  if (t < GS) {
    int idx = widx[t];
    int o = ((b * NG + g) * GS + t) * 3;
    out[o + 0] = bx[idx];
    out[o + 1] = by[idx];
    out[o + 2] = bz[idx];
  }
}

extern "C" void kernel_launch(void* const* d_in, const int* in_sizes, int n_in,
                              void* d_out, int out_size, void* d_ws, size_t ws_size,
                              hipStream_t stream) {
  const float* xyz = (const float*)d_in[0];   // (B, N, 3) f32
  const float* pose = (const float*)d_in[1];  // (B, 3, 4) f32
  float* out = (float*)d_out;                 // neighborhood (B,NG,GS,3) ++ center (B,NG,3)

  float* xs = (float*)d_ws;       // SoA transformed points
  float* ys = xs + B * N;
  float* zs = ys + B * N;
  ull* comm = (ull*)(zs + B * N);  // 8 batches x 2 parities x 4 slots = 64 u64
  float* centers = out + B * NG * GS * 3;  // center block of d_out

  transform_k<<<dim3((B * N + 255) / 256), dim3(256), 0, stream>>>(xyz, pose, xs, ys, zs, comm);
  fps_k<<<dim3(B * FPS_Q), dim3(FPS_T), 0, stream>>>(xs, ys, zs, centers, comm);
  knn_k<<<dim3(NG, B), dim3(KNN_T), 0, stream>>>(xs, ys, zs, centers, out);
}

// Round 4
// 714.822 us; speedup vs baseline: 1.2884x; 1.2884x over previous
//
#include <hip/hip_runtime.h>
#include <stdint.h>

#define B 8
#define N 8192
#define NG 512
#define GS 32

typedef unsigned long long ull;
typedef float v2f __attribute__((ext_vector_type(2)));

// Exact (no-FMA, left-to-right) squared distance: ((dx*dx + dy*dy) + dz*dz)
__device__ __forceinline__ float sq3(float dx, float dy, float dz) {
#pragma clang fp contract(off)
  return dx * dx + dy * dy + dz * dz;
}

// 64-bit max/min via DPP move (pure VALU, no LDS pipe). Invalid lanes keep old.
template <int CTRL>
__device__ __forceinline__ ull dpp_max64(ull key) {
  unsigned lo = (unsigned)key, hi = (unsigned)(key >> 32);
  unsigned olo = (unsigned)__builtin_amdgcn_update_dpp((int)lo, (int)lo, CTRL, 0xf, 0xf, false);
  unsigned ohi = (unsigned)__builtin_amdgcn_update_dpp((int)hi, (int)hi, CTRL, 0xf, 0xf, false);
  ull o = ((ull)ohi << 32) | olo;
  return (o > key) ? o : key;
}
template <int CTRL>
__device__ __forceinline__ ull dpp_min64(ull key) {
  unsigned lo = (unsigned)key, hi = (unsigned)(key >> 32);
  unsigned olo = (unsigned)__builtin_amdgcn_update_dpp((int)lo, (int)lo, CTRL, 0xf, 0xf, false);
  unsigned ohi = (unsigned)__builtin_amdgcn_update_dpp((int)hi, (int)hi, CTRL, 0xf, 0xf, false);
  ull o = ((ull)ohi << 32) | olo;
  return (o < key) ? o : key;
}

// ---------------- Kernel 1: SE(3) transform, AoS xyz -> SoA xs/ys/zs ------
__global__ void transform_k(const float* __restrict__ xyz,
                            const float* __restrict__ pose,
                            float* __restrict__ xs, float* __restrict__ ys,
                            float* __restrict__ zs) {
#pragma clang fp contract(off)
  int i = blockIdx.x * blockDim.x + threadIdx.x;
  if (i >= B * N) return;
  int b = i / N;
  const float* P = pose + b * 12;  // (3,4) row-major: R|t
  float p0 = xyz[i * 3 + 0], p1 = xyz[i * 3 + 1], p2 = xyz[i * 3 + 2];
  // exact order: ((r0*p0 + r1*p1) + r2*p2) + t
  float ox = ((P[0] * p0 + P[1] * p1) + P[2] * p2) + P[3];
  float oy = ((P[4] * p0 + P[5] * p1) + P[6] * p2) + P[7];
  float oz = ((P[8] * p0 + P[9] * p1) + P[10] * p2) + P[11];
  xs[i] = ox;
  ys[i] = oy;
  zs[i] = oz;
}

// ---------------- Kernel 2: farthest point sampling, 1 block per batch ----
// 256 threads (4 waves), 16 float2 (=32 points) per thread, ONE barrier/step.
// Fused update+argmax single pass; DPP (VALU) wave reduction; LDS point
// mirror for winner coords. Centers buffered in LDS (cbuf) so NO global
// store is outstanding at the per-step barrier (the compiler drains
// vmcnt(0) before s_barrier -> a per-step global store would put a
// store-to-L2 round trip on the critical path of every step).
#define FPS_T 256
#define FPS_W (FPS_T / 64)      // 4 waves
#define FPS_J (N / FPS_T / 2)   // 16 float2 per thread

__global__ __launch_bounds__(FPS_T) void fps_k(const float* __restrict__ xs,
                                               const float* __restrict__ ys,
                                               const float* __restrict__ zs,
                                               float* __restrict__ centers) {
#pragma clang fp contract(off)
  int b = blockIdx.x;
  int t = threadIdx.x;

  __shared__ float plx[N];            // LDS mirror of this batch's points (SoA)
  __shared__ float ply[N];
  __shared__ float plz[N];
  __shared__ float cbuf[NG * 3];      // buffered centers (flush at end)
  __shared__ ull wkey[2][FPS_W];      // double-buffered per-wave winner keys
  __shared__ float4 wxyz[2][FPS_W];   // ... and winner coords

  const float* __restrict__ bx = xs + b * N;
  const float* __restrict__ by = ys + b * N;
  const float* __restrict__ bz = zs + b * N;
  const v2f* __restrict__ bx2 = (const v2f*)bx;
  const v2f* __restrict__ by2 = (const v2f*)by;
  const v2f* __restrict__ bz2 = (const v2f*)bz;

  // point (j, t, e) has global index p = (j*FPS_T + t)*2 + e
  v2f px[FPS_J], py[FPS_J], pz[FPS_J], dist[FPS_J];
#pragma unroll
  for (int j = 0; j < FPS_J; ++j) {
    int q = j * FPS_T + t;
    px[j] = bx2[q];
    py[j] = by2[q];
    pz[j] = bz2[q];
    ((v2f*)plx)[q] = px[j];  // stage LDS mirror
    ((v2f*)ply)[q] = py[j];
    ((v2f*)plz)[q] = pz[j];
    dist[j].x = 1e10f;  // matches jnp.full(..., 1e10, f32)
    dist[j].y = 1e10f;
  }

  // initial "last" point is index 0 (broadcast global load, off critical path)
  float lx = bx[0], ly = by[0], lz = bz[0];
  __syncthreads();  // LDS mirror ready

  for (int k = 0; k < NG; ++k) {
    if (t == 0) {  // emit 'last' BEFORE update; LDS store (no vmcnt at barrier)
      cbuf[k * 3 + 0] = lx;
      cbuf[k * 3 + 1] = ly;
      cbuf[k * 3 + 2] = lz;
    }

    // Fused exact min-update + first-occurrence argmax.
    // 4 independent (best,code) accumulators keep the cndmask chain short.
    // code = j*2+e  (within-thread idx order ascending => strict '>' keeps
    // the first occurrence inside each accumulator's subsequence).
    float bd0 = -1.0f, bd1 = -1.0f, bd2 = -1.0f, bd3 = -1.0f;
    int bc0 = 0, bc1 = 0, bc2 = 0, bc3 = 0;
#pragma unroll
    for (int j = 0; j < FPS_J; ++j) {
      v2f dx = px[j] - lx, dy = py[j] - ly, dz = pz[j] - lz;
      v2f d = (dx * dx + dy * dy) + dz * dz;
      v2f dm;
      dm.x = fminf(dist[j].x, d.x);
      dm.y = fminf(dist[j].y, d.y);
      dist[j] = dm;
      int a = j & 3;
      float* bdp = (a == 0) ? &bd0 : (a == 1) ? &bd1 : (a == 2) ? &bd2 : &bd3;
      int* bcp = (a == 0) ? &bc0 : (a == 1) ? &bc1 : (a == 2) ? &bc2 : &bc3;
      bool g0 = dm.x > *bdp;
      *bdp = g0 ? dm.x : *bdp;
      *bcp = g0 ? (2 * j) : *bcp;
      bool g1 = dm.y > *bdp;
      *bdp = g1 ? dm.y : *bdp;
      *bcp = g1 ? (2 * j + 1) : *bcp;
    }
    // tie-aware merges: equal dist -> smaller code (codes are in idx order)
    {
      bool s1 = (bd1 > bd0) || ((bd1 == bd0) && (bc1 < bc0));
      bd0 = s1 ? bd1 : bd0; bc0 = s1 ? bc1 : bc0;
      bool s2 = (bd3 > bd2) || ((bd3 == bd2) && (bc3 < bc2));
      bd2 = s2 ? bd3 : bd2; bc2 = s2 ? bc3 : bc2;
      bool s3 = (bd2 > bd0) || ((bd2 == bd0) && (bc2 < bc0));
      bd0 = s3 ? bd2 : bd0; bc0 = s3 ? bc2 : bc0;
    }
    // reconstruct global point index: idx = (j*FPS_T + t)*2 + e
    int cand = (bc0 >> 1) * (FPS_T * 2) + t * 2 + (bc0 & 1);
    // pack: max over key == max dist, tie -> min index
    ull key = ((ull)__float_as_uint(bd0) << 32) | (ull)(unsigned)(N - 1 - cand);

    // wave-level max via DPP (VALU only): row_shr 1/2/4/8, bcast 15/31
    key = dpp_max64<0x111>(key);
    key = dpp_max64<0x112>(key);
    key = dpp_max64<0x114>(key);
    key = dpp_max64<0x118>(key);
    key = dpp_max64<0x142>(key);
    key = dpp_max64<0x143>(key);
    // lane 63 holds the wave max; broadcast via readlane (uniform SGPR)
    unsigned klo = (unsigned)__builtin_amdgcn_readlane((int)(unsigned)key, 63);
    unsigned khi = (unsigned)__builtin_amdgcn_readlane((int)(unsigned)(key >> 32), 63);
    ull wk = ((ull)khi << 32) | klo;

    int kb = k & 1;
    if ((t & 63) == 0) {
      // decode wave winner, fetch coords from LDS mirror (pre-barrier overlap)
      int wc = (N - 1) - (int)(unsigned)(wk & 0xffffffffu);
      wkey[kb][t >> 6] = wk;
      wxyz[kb][t >> 6] = make_float4(plx[wc], ply[wc], plz[wc], 0.0f);
    }
    __syncthreads();

    // cross-wave serial reduce over 4 partials, selecting coords with the key
    ull gk = wkey[kb][0];
    float4 c0 = wxyz[kb][0];
    float cx = c0.x, cy = c0.y, cz = c0.z;
#pragma unroll
    for (int w = 1; w < FPS_W; ++w) {
      ull o = wkey[kb][w];
      float4 oc = wxyz[kb][w];
      bool sw = o > gk;
      gk = sw ? o : gk;
      cx = sw ? oc.x : cx;
      cy = sw ? oc.y : cy;
      cz = sw ? oc.z : cz;
    }
    lx = cx;
    ly = cy;
    lz = cz;
    // no second barrier: next iter writes wkey/wxyz[(k+1)&1] (other buffer)
  }

  // flush centers (B, NG, 3)
  __syncthreads();
  for (int i = t; i < NG * 3; i += FPS_T) centers[b * NG * 3 + i] = cbuf[i];
}

// ---------------- Kernel 3: exact 32-NN per center, 1 block per center ----
// DPP (VALU) u64-min wave reduction + parity-double-buffered partials:
// ONE barrier per extraction round (plus one final before the gather).
#define KNN_T 256
#define KNN_W (KNN_T / 64)
#define KNN_P (N / KNN_T)  // 32 points per thread

__global__ __launch_bounds__(KNN_T) void knn_k(const float* __restrict__ xs,
                                               const float* __restrict__ ys,
                                               const float* __restrict__ zs,
                                               const float* __restrict__ centers,
                                               float* __restrict__ out) {
#pragma clang fp contract(off)
  int b = blockIdx.y, g = blockIdx.x, t = threadIdx.x;
  const float* bx = xs + b * N;
  const float* by = ys + b * N;
  const float* bz = zs + b * N;
  int ci = (b * NG + g) * 3;
  float cx = centers[ci], cy = centers[ci + 1], cz = centers[ci + 2];

  // packed keys: (distBits<<32)|idx ; min over key == min dist, tie -> min idx
  ull key[KNN_P];
  ull lmin = ~0ull;
#pragma unroll
  for (int j = 0; j < KNN_P; ++j) {
    int p = j * KNN_T + t;
    float dx = bx[p] - cx, dy = by[p] - cy, dz = bz[p] - cz;
    float d = sq3(dx, dy, dz);
    key[j] = ((ull)__float_as_uint(d) << 32) | (ull)(unsigned)p;
    lmin = (key[j] < lmin) ? key[j] : lmin;
  }

  __shared__ ull wred[2][KNN_W];  // parity-double-buffered per-wave minima
  __shared__ int widx[GS];

  for (int k = 0; k < GS; ++k) {
    int kb = k & 1;
    ull v = lmin;
    // wave-level min via DPP (VALU only): row_shr 1/2/4/8, bcast 15/31
    v = dpp_min64<0x111>(v);
    v = dpp_min64<0x112>(v);
    v = dpp_min64<0x114>(v);
    v = dpp_min64<0x118>(v);
    v = dpp_min64<0x142>(v);
    v = dpp_min64<0x143>(v);
    unsigned vlo = (unsigned)__builtin_amdgcn_readlane((int)(unsigned)v, 63);
    unsigned vhi = (unsigned)__builtin_amdgcn_readlane((int)(unsigned)(v >> 32), 63);
    ull wv = ((ull)vhi << 32) | vlo;

    if ((t & 63) == 0) wred[kb][t >> 6] = wv;
    __syncthreads();

    ull gm = wred[kb][0];
#pragma unroll
    for (int w = 1; w < KNN_W; ++w) {
      ull o = wred[kb][w];
      gm = (o < gm) ? o : gm;
    }
    int idx = (int)(unsigned)gm;

    // only the owning lane rescans its keys (cached local min elsewhere)
    if (t == (idx & (KNN_T - 1))) {
      int jj = idx / KNN_T;
#pragma unroll
      for (int j = 0; j < KNN_P; ++j)
        if (j == jj) key[j] = ~0ull;
      lmin = ~0ull;
#pragma unroll
      for (int j = 0; j < KNN_P; ++j) lmin = (key[j] < lmin) ? key[j] : lmin;
    }
    if (t == 0) widx[k] = idx;
    // no second barrier: next round writes wred[(k+1)&1] (other buffer);
    // wred[kb] can't be overwritten before all waves read it (barrier k+1
    // can't complete until every wave has passed its wred[kb] read).
  }
  __syncthreads();  // widx fully written

  // gather & write neighborhood (B, NG, GS, 3), k ascending by (d, idx)
  if (t < GS) {
    int idx = widx[t];
    int o = ((b * NG + g) * GS + t) * 3;
    out[o + 0] = bx[idx];
    out[o + 1] = by[idx];
    out[o + 2] = bz[idx];
  }
}

extern "C" void kernel_launch(void* const* d_in, const int* in_sizes, int n_in,
                              void* d_out, int out_size, void* d_ws, size_t ws_size,
                              hipStream_t stream) {
  const float* xyz = (const float*)d_in[0];   // (B, N, 3) f32
  const float* pose = (const float*)d_in[1];  // (B, 3, 4) f32
  float* out = (float*)d_out;                 // neighborhood (B,NG,GS,3) ++ center (B,NG,3)

  float* xs = (float*)d_ws;       // SoA transformed points
  float* ys = xs + B * N;
  float* zs = ys + B * N;
  float* centers = out + B * NG * GS * 3;  // center block of d_out

  transform_k<<<dim3((B * N + 255) / 256), dim3(256), 0, stream>>>(xyz, pose, xs, ys, zs);
  fps_k<<<dim3(B), dim3(FPS_T), 0, stream>>>(xs, ys, zs, centers);
  knn_k<<<dim3(NG, B), dim3(KNN_T), 0, stream>>>(xs, ys, zs, centers, out);
}